// Round 11
// baseline (395.404 us; speedup 1.0000x reference)
//
#include <hip/hip_runtime.h>
#include <cstdint>
#include <cstddef>

// ---------------- problem constants ----------------
#define HH 208
#define WW 336
#define NA 3
#define NPER 209664      // H*W*A per image
#define NROWS 139776     // B*H*W
#define RPI 69888        // H*W rows per image
#define NB 2
#define PRE_K 2000
#define POST_K 1000
#define CAP 8192         // candidate capacity per image (power of 2 for bitonic)
#define MW 32            // 64-bit words per mask row (32*64 = 2048 >= 2000)
#define MROWS 2048
#define BBOX_CLIP_F 4.135166556742356f

// ---------------- ws layout (bytes) ----------------
#define WS_HIST   0
#define WS_HIST2  32768
#define WS_META   65536
#define WS_META24 65544
#define WS_CCNT   65552
#define WS_KEEPW  65568
#define WS_CAND   66080
#define WS_SBOX   197152
#define WS_SSC    261152
#define WS_MASK   277248
// zero [0, WS_KEEPW): hist, hist2, meta, counts. cand not zeroed
// (k_sort guards i<cc).
#define WS_ZERO_WORDS 16392

// ---------------- helpers ----------------
__device__ __forceinline__ float sigmoidf_ref(float x) {
  return __fdiv_rn(1.0f, __fadd_rn(1.0f, expf(-x)));
}
__device__ __forceinline__ unsigned int score_u(float logit) {
  float s = sigmoidf_ref(logit);            // s in (0,1), sign bit 0
  return __float_as_uint(s) | 0x80000000u;  // orderable
}

// broadcast 64-bit value from lane l (uniform l) via v_readlane — no LDS round trip
__device__ __forceinline__ unsigned long long bcast64(unsigned long long v, int l) {
  unsigned int lo = (unsigned int)__builtin_amdgcn_readlane((int)(unsigned int)v, l);
  unsigned int hi = (unsigned int)__builtin_amdgcn_readlane((int)(unsigned int)(v >> 32), l);
  return ((unsigned long long)hi << 32) | lo;
}

// descending suffix-select over a 4096-bin histogram, 256 threads.
// Finds the bin where C0in + suffix count crosses `need`; crossing thread
// writes (base|bin) to *outBin and optionally the strictly-above count to
// *outC0. Integer math identical to the original k_thresh/k_thresh2.
// Requires blockDim.x == 256; csum is 256 u32 of LDS scratch.
__device__ __forceinline__ void suffix_select(const unsigned int* __restrict__ H,
                                              unsigned int C0in, unsigned int need,
                                              unsigned int base,
                                              unsigned int* __restrict__ csum,
                                              unsigned int* __restrict__ outBin,
                                              unsigned int* __restrict__ outC0) {
  const int t = threadIdx.x;
  unsigned int hb[16];
  unsigned int s = 0u;
#pragma unroll
  for (int q = 0; q < 16; ++q) {
    hb[q] = H[4095 - (t * 16 + q)];
    s += hb[q];
  }
  csum[t] = s;
  __syncthreads();
  for (int off = 1; off < 256; off <<= 1) {
    unsigned int v = (t >= off) ? csum[t - off] : 0u;
    __syncthreads();
    csum[t] += v;
    __syncthreads();
  }
  unsigned int excl = C0in + (csum[t] - s);
  if (excl < need && excl + s >= need) {
    unsigned int c = excl;
#pragma unroll
    for (int q = 0; q < 16; ++q) {
      c += hb[q];
      if (c >= need) {
        *outBin = base | (unsigned int)(4095 - (t * 16 + q));
        if (outC0) *outC0 = c - hb[q];
        break;
      }
    }
  }
}

// decode box for anchor n of image b; matches reference op-by-op (no FMA contraction)
__device__ __forceinline__ float4 decode_box(const float* __restrict__ bbox,
                                             int b, unsigned int n,
                                             float hmax, float wmax) {
  unsigned int a = n % 3u;
  unsigned int pix = n / 3u;
  unsigned int y = pix / (unsigned int)WW;
  unsigned int x = pix % (unsigned int)WW;
  float yc = ((float)y + 0.5f) * 4.0f;   // exact in f32
  float xc = ((float)x + 0.5f) * 4.0f;   // exact in f32
  float hx = (a == 0) ? 16.0f : ((a == 1) ? 22.4f : 11.2f);
  float hy = (a == 0) ? 16.0f : ((a == 1) ? 11.2f : 22.4f);
  float ay1 = __fsub_rn(yc, hy), ax1 = __fsub_rn(xc, hx);
  float ay2 = __fadd_rn(yc, hy), ax2 = __fadd_rn(xc, hx);
  float ah = __fsub_rn(ay2, ay1), aw = __fsub_rn(ax2, ax1);
  float acy = __fadd_rn(ay1, __fmul_rn(0.5f, ah));
  float acx = __fadd_rn(ax1, __fmul_rn(0.5f, aw));
  const float* d = bbox + ((size_t)b * NPER + n) * 4u;
  float dy = d[0], dx = d[1];
  float dh = fminf(fmaxf(d[2], -BBOX_CLIP_F), BBOX_CLIP_F);
  float dw = fminf(fmaxf(d[3], -BBOX_CLIP_F), BBOX_CLIP_F);
  float cy = __fadd_rn(__fmul_rn(dy, ah), acy);
  float cx = __fadd_rn(__fmul_rn(dx, aw), acx);
  float hh = __fmul_rn(expf(dh), ah);
  float wwv = __fmul_rn(expf(dw), aw);
  float y1 = __fsub_rn(cy, __fmul_rn(0.5f, hh));
  float x1 = __fsub_rn(cx, __fmul_rn(0.5f, wwv));
  float y2 = __fadd_rn(cy, __fmul_rn(0.5f, hh));
  float x2 = __fadd_rn(cx, __fmul_rn(0.5f, wwv));
  y1 = fminf(fmaxf(y1, 0.0f), hmax);
  x1 = fminf(fmaxf(x1, 0.0f), wmax);
  y2 = fminf(fmaxf(y2, 0.0f), hmax);
  x2 = fminf(fmaxf(x2, 0.0f), wmax);
  return make_float4(y1, x1, y2, x2);
}

// reference IoU, exact op order
__device__ __forceinline__ float iou_ref(float4 bi, float4 bj) {
  float yA = fmaxf(bi.x, bj.x);
  float xA = fmaxf(bi.y, bj.y);
  float yB = fminf(bi.z, bj.z);
  float xB = fminf(bi.w, bj.w);
  float inter = __fmul_rn(fmaxf(__fsub_rn(yB, yA), 0.0f),
                          fmaxf(__fsub_rn(xB, xA), 0.0f));
  float a1 = __fmul_rn(__fsub_rn(bi.z, bi.x), __fsub_rn(bi.w, bi.y));
  float a2 = __fmul_rn(__fsub_rn(bj.z, bj.x), __fsub_rn(bj.w, bj.y));
  float den = __fadd_rn(__fsub_rn(__fadd_rn(a1, a2), inter), 1e-8f);
  return __fdiv_rn(inter, den);
}

// ---------------- K0: zero ws prefix ----------------
__global__ void k_zero(unsigned int* __restrict__ p, int n) {
  int i = blockIdx.x * blockDim.x + threadIdx.x;
  if (i < n) p[i] = 0u;
}

// ---------------- K1: head GEMM + fused coarse histogram ----------------
// R7-best body (392.7us). Occupancy ledger (all measured): 3w+2row=392.7,
// 3w+1row=396.3 (R8), 4w+1row=402.3 (R9) — 2-row ILP at 3 waves/SIMD wins.
__global__ __launch_bounds__(256, 3) void k_head(
    const float* __restrict__ feats, const float* __restrict__ w_cls,
    const float* __restrict__ b_cls, const float* __restrict__ w_reg,
    const float* __restrict__ b_reg, float* __restrict__ out_cls,
    float* __restrict__ out_bbox, unsigned int* __restrict__ hist) {
  const int b = blockIdx.y;
  const int lane = threadIdx.x & 63;
  const int wid = blockIdx.x * (blockDim.x >> 6) + (threadIdx.x >> 6);
  const int nw = gridDim.x * (blockDim.x >> 6);
  const int k0 = lane << 2;
  const int l15 = lane & 15;
  const int ol = ((l15 & 1) << 3) | ((l15 & 2) << 1) | ((l15 & 4) >> 1) |
                 ((l15 & 8) >> 3);  // brev4 — this lane's final output

  __shared__ unsigned int h[4096];     // 16 KiB
  __shared__ float wt[16][256];        // 16 KiB, wt[o][c]
  for (int i = threadIdx.x; i < 4096; i += blockDim.x) {
    h[i] = 0u;
    const int o = i >> 8, c = i & 255;
    wt[o][c] = (o < 3) ? w_cls[c * 3 + o]
                       : (o < 15 ? w_reg[c * 12 + (o - 3)] : 0.0f);
  }
  __syncthreads();

  // one-time weight fetch into named registers: wj = wt[ol^j][k0..k0+3]
  float4 w0  = *(const float4*)&wt[ol ^ 0][k0];
  float4 w1  = *(const float4*)&wt[ol ^ 1][k0];
  float4 w2  = *(const float4*)&wt[ol ^ 2][k0];
  float4 w3  = *(const float4*)&wt[ol ^ 3][k0];
  float4 w4  = *(const float4*)&wt[ol ^ 4][k0];
  float4 w5  = *(const float4*)&wt[ol ^ 5][k0];
  float4 w6  = *(const float4*)&wt[ol ^ 6][k0];
  float4 w7  = *(const float4*)&wt[ol ^ 7][k0];
  float4 w8  = *(const float4*)&wt[ol ^ 8][k0];
  float4 w9  = *(const float4*)&wt[ol ^ 9][k0];
  float4 w10 = *(const float4*)&wt[ol ^ 10][k0];
  float4 w11 = *(const float4*)&wt[ol ^ 11][k0];
  float4 w12 = *(const float4*)&wt[ol ^ 12][k0];
  float4 w13 = *(const float4*)&wt[ol ^ 13][k0];
  float4 w14 = *(const float4*)&wt[ol ^ 14][k0];
  float4 w15 = *(const float4*)&wt[ol ^ 15][k0];
  float bias = (ol < 3) ? b_cls[ol] : (ol < 15 ? b_reg[ol - 3] : 0.0f);

  // pin: values become opaque -> compiler must keep them register-resident.
#define PIN4(W) asm volatile("" : "+v"(W.x), "+v"(W.y), "+v"(W.z), "+v"(W.w))
  PIN4(w0);  PIN4(w1);  PIN4(w2);  PIN4(w3);
  PIN4(w4);  PIN4(w5);  PIN4(w6);  PIN4(w7);
  PIN4(w8);  PIN4(w9);  PIN4(w10); PIN4(w11);
  PIN4(w12); PIN4(w13); PIN4(w14); PIN4(w15);
#undef PIN4
  asm volatile("" : "+v"(bias));

  for (int rr = wid; rr < RPI; rr += 2 * nw) {
    const int rr1 = rr + nw;
    const int has1 = (rr1 < RPI);
    const int r0 = b * RPI + rr;
    const int r1 = b * RPI + (has1 ? rr1 : rr);
    const float4 f0 = *(const float4*)(feats + (size_t)r0 * 256 + k0);
    const float4 f1 = *(const float4*)(feats + (size_t)r1 * 256 + k0);
    float a0[16], a1[16];
#define STEPJ(J, W)                                                        \
    {                                                                      \
      a0[J] = f0.x * W.x; a0[J] += f0.y * W.y;                             \
      a0[J] += f0.z * W.z; a0[J] += f0.w * W.w;                            \
      a1[J] = f1.x * W.x; a1[J] += f1.y * W.y;                             \
      a1[J] += f1.z * W.z; a1[J] += f1.w * W.w;                            \
    }
    STEPJ(0, w0)   STEPJ(1, w1)   STEPJ(2, w2)   STEPJ(3, w3)
    STEPJ(4, w4)   STEPJ(5, w5)   STEPJ(6, w6)   STEPJ(7, w7)
    STEPJ(8, w8)   STEPJ(9, w9)   STEPJ(10, w10) STEPJ(11, w11)
    STEPJ(12, w12) STEPJ(13, w13) STEPJ(14, w14) STEPJ(15, w15)
#undef STEPJ
#pragma unroll
    for (int s = 0; s < 8; ++s) {
      a0[s] += __shfl_xor(a0[8 + s], 1, 64);
      a1[s] += __shfl_xor(a1[8 + s], 1, 64);
    }
#pragma unroll
    for (int s = 0; s < 4; ++s) {
      a0[s] += __shfl_xor(a0[4 + s], 2, 64);
      a1[s] += __shfl_xor(a1[4 + s], 2, 64);
    }
#pragma unroll
    for (int s = 0; s < 2; ++s) {
      a0[s] += __shfl_xor(a0[2 + s], 4, 64);
      a1[s] += __shfl_xor(a1[2 + s], 4, 64);
    }
    a0[0] += __shfl_xor(a0[1], 8, 64);
    a1[0] += __shfl_xor(a1[1], 8, 64);
    a0[0] += __shfl_xor(a0[0], 16, 64);
    a1[0] += __shfl_xor(a1[0], 16, 64);
    a0[0] += __shfl_xor(a0[0], 32, 64);
    a1[0] += __shfl_xor(a1[0], 32, 64);
    if (lane < 16 && ol < 15) {
      float v0 = a0[0] + bias;
      if (ol < 3) {
        out_cls[(size_t)r0 * 3 + ol] = v0;
        atomicAdd(&h[score_u(v0) >> 20], 1u);
      } else {
        out_bbox[(size_t)r0 * 12 + (ol - 3)] = v0;
      }
      if (has1) {
        float v1 = a1[0] + bias;
        if (ol < 3) {
          out_cls[(size_t)r1 * 3 + ol] = v1;
          atomicAdd(&h[score_u(v1) >> 20], 1u);
        } else {
          out_bbox[(size_t)r1 * 12 + (ol - 3)] = v1;
        }
      }
    }
  }
  __syncthreads();
  // scores cluster near 0.5 → only a handful of nonzero bins per block
  for (int i = threadIdx.x; i < 4096; i += blockDim.x)
    if (h[i]) atomicAdd(&hist[b * 4096 + i], h[i]);
}

// ---------------- K2: refine histogram (T computed redundantly per block) --
__global__ __launch_bounds__(256) void k_hist2(const float* __restrict__ out_cls,
                                               const unsigned int* __restrict__ hist,
                                               unsigned int* __restrict__ hist2) {
  const int b = blockIdx.y;
  __shared__ unsigned int h[4096];
  __shared__ unsigned int csum[256];
  __shared__ unsigned int Tsh;
  for (int i = threadIdx.x; i < 4096; i += blockDim.x) h[i] = 0u;
  suffix_select(hist + b * 4096, 0u, PRE_K, 0u, csum, &Tsh, nullptr);
  __syncthreads();
  const unsigned int T = Tsh;
  for (int i = blockIdx.x * blockDim.x + threadIdx.x; i < NPER;
       i += gridDim.x * blockDim.x) {
    unsigned int u = score_u(out_cls[(size_t)b * NPER + i]);
    if ((u >> 20) == T) atomicAdd(&h[(u >> 8) & 0xFFFu], 1u);
  }
  __syncthreads();
  for (int i = threadIdx.x; i < 4096; i += blockDim.x)
    if (h[i]) atomicAdd(&hist2[b * 4096 + i], h[i]);
}

// ---------------- K3: compact (T24 computed redundantly per block) ---------
__global__ __launch_bounds__(256) void k_compact(const float* __restrict__ out_cls,
                                                 const unsigned int* __restrict__ hist,
                                                 const unsigned int* __restrict__ hist2,
                                                 unsigned int* __restrict__ cand_count,
                                                 unsigned long long* __restrict__ cand) {
  const int b = blockIdx.y;
  __shared__ unsigned int csum[256];
  __shared__ unsigned int Tsh, C0sh, T24sh;
  suffix_select(hist + b * 4096, 0u, PRE_K, 0u, csum, &Tsh, &C0sh);
  __syncthreads();
  const unsigned int T = Tsh, C0 = C0sh;
  suffix_select(hist2 + b * 4096, C0, PRE_K, T << 12, csum, &T24sh, nullptr);
  __syncthreads();
  const unsigned int T24 = T24sh;
  for (int i = blockIdx.x * blockDim.x + threadIdx.x; i < NPER;
       i += gridDim.x * blockDim.x) {
    unsigned int u = score_u(out_cls[(size_t)b * NPER + i]);
    if ((u >> 8) >= T24) {
      unsigned int pos = atomicAdd(&cand_count[b], 1u);
      if (pos < CAP)
        cand[(size_t)b * CAP + pos] =
            ((unsigned long long)u << 32) | (unsigned int)(~(unsigned int)i);
    }
  }
}

// ---------------- K4: adaptive bitonic sort (desc) + gather/decode top-2000 -
__global__ __launch_bounds__(1024) void k_sort(const unsigned long long* __restrict__ cand,
                                               const unsigned int* __restrict__ cand_count,
                                               const float* __restrict__ out_bbox,
                                               const float* __restrict__ img_info,
                                               float* __restrict__ sboxes,
                                               float* __restrict__ sscores) {
  const int b = blockIdx.x;
  const int t = threadIdx.x;
  __shared__ unsigned long long keys[CAP];   // 64 KiB
  unsigned int cc = cand_count[b];
  if (cc > CAP) cc = CAP;
  int n = 2048;
  while ((unsigned int)n < cc) n <<= 1;
  for (int i = t; i < n; i += 1024)
    keys[i] = (i < (int)cc) ? cand[(size_t)b * CAP + i] : 0ull;
  __syncthreads();
  for (int k = 2; k <= n; k <<= 1) {
    for (int j = k >> 1; j > 0; j >>= 1) {
      for (int i = t; i < n; i += 1024) {
        int ixj = i ^ j;
        if (ixj > i) {
          unsigned long long a = keys[i], c = keys[ixj];
          bool up = ((i & k) == 0);
          bool sw = up ? (a < c) : (a > c);   // descending overall
          if (sw) { keys[i] = c; keys[ixj] = a; }
        }
      }
      __syncthreads();
    }
  }
  const float hmax = img_info[b * 2 + 0];
  const float wmax = img_info[b * 2 + 1];
  for (int i = t; i < PRE_K; i += 1024) {
    unsigned long long key = keys[i];
    unsigned int u = (unsigned int)(key >> 32);
    unsigned int idx = ~(unsigned int)(key & 0xFFFFFFFFull);
    float sc = __uint_as_float(u & 0x7FFFFFFFu);
    float4 bx = decode_box(out_bbox, b, idx, hmax, wmax);
    ((float4*)sboxes)[(size_t)b * PRE_K + i] = bx;
    sscores[(size_t)b * PRE_K + i] = sc;
  }
}

// ---------------- K5: pairwise suppression mask (upper-triangle grid) ------
__global__ __launch_bounds__(64) void k_mask(const float* __restrict__ sboxes,
                                             unsigned long long* __restrict__ mask) {
  const int b = blockIdx.z;
  const int p = blockIdx.x;
  const int q = 527 - p;
  const int kk = (int)((sqrtf((float)(8 * q + 1)) - 1.0f) * 0.5f);
  const int rb = 31 - kk;
  const int cb = 31 - (q - kk * (kk + 1) / 2);
  const int t = threadIdx.x;
  __shared__ float4 cbox[64];
  const int col0 = cb * 64;
  {
    int c = col0 + t;
    cbox[t] = (c < PRE_K) ? ((const float4*)sboxes)[(size_t)b * PRE_K + c]
                          : make_float4(0.f, 0.f, 0.f, 0.f);
  }
  __syncthreads();
  const int i = rb * 64 + t;
  if (i >= PRE_K) return;
  float4 bi = ((const float4*)sboxes)[(size_t)b * PRE_K + i];
  unsigned long long bits = 0ull;
#pragma unroll 8
  for (int j = 0; j < 64; ++j) {
    int c = col0 + j;
    if (c > i && c < PRE_K) {
      if (iou_ref(bi, cbox[j]) > 0.7f) bits |= (1ull << j);
    }
  }
  mask[((size_t)b * MROWS + i) * MW + cb] = bits;
}

// ---------------- K6: keep scan + rank write (merged) ----------------
// v2: the 64 prefetched mask words per lane are NAMED u64 scalars (no alloca)
// and the kernel requests waves_per_eu(1) for the full VGPR file. R10
// counters showed VGPR_Count=72 — the old u64[32]x2 arrays CANNOT have been
// register-resident (need >=128), so the intended group-ahead prefetch was
// spilled/sunk to memory: k_scan ran 93us at 0.03% VALUBusy (pure serialized
// latency). Same algorithm, same load indices, bit-identical keep set.
#define REP32(F)                                                          \
  F(0) F(1) F(2) F(3) F(4) F(5) F(6) F(7)                                 \
  F(8) F(9) F(10) F(11) F(12) F(13) F(14) F(15)                           \
  F(16) F(17) F(18) F(19) F(20) F(21) F(22) F(23)                         \
  F(24) F(25) F(26) F(27) F(28) F(29) F(30) F(31)

#define DECLM(K) unsigned long long mA##K, mB##K;
// load group gg's word for rows 2K+psel, column lane&31 (upper-triangle only)
#define MLA(K) mA##K = ((gg * 64 + 2 * K + psel) < PRE_K && (lane & 31) >= gg) \
                           ? M[(size_t)gg * 2048 + 64 * K + lane] : 0ull;
#define MLB(K) mB##K = ((gg * 64 + 2 * K + psel) < PRE_K && (lane & 31) >= gg) \
                           ? M[(size_t)gg * 2048 + 64 * K + lane] : 0ull;
#define UPDA(K) { unsigned long long sel_ = 0ull - ((keptv >> (2 * K)) & 1ull); \
                  remv |= mA##K & sel_; }
#define UPDB(K) { unsigned long long sel_ = 0ull - ((keptv >> (2 * K)) & 1ull); \
                  remv |= mB##K & sel_; }

#define GSTEP_CORE(G, MLOADNEXT, UPDCUR, DCUR, DNEXT)                     \
  do {                                                                    \
    { const int gg = (G) + 1; REP32(MLOADNEXT) }                          \
    { int _row = ((G) + 1) * 64 + lane;                                   \
      (DNEXT) = (((G) + 1) < 32 && _row < PRE_K)                          \
                    ? M[(size_t)_row * MW + ((G) + 1)] : 0ull; }          \
    unsigned long long w = bcast64(remv, (G)) | bcast64(remv, (G) + 32);  \
    unsigned long long alive = ~w;                                        \
    if ((G) == 31) alive &= (1ull << (PRE_K - 31 * 64)) - 1ull;           \
    unsigned long long kept = 0ull;                                       \
    while (alive) {                                                       \
      int j = __builtin_ctzll(alive);                                     \
      unsigned long long bit = 1ull << j;                                 \
      kept |= bit;                                                        \
      unsigned long long dj = bcast64((DCUR), j);                         \
      alive &= ~(dj | bit);                                               \
    }                                                                     \
    int pc = __popcll(kept);                                              \
    if (nk + pc >= POST_K) {                                              \
      int need = POST_K - nk;                                             \
      unsigned long long k2 = kept;                                       \
      for (int _t = 0; _t < need; ++_t) k2 &= k2 - 1;                     \
      kept ^= k2;   /* keep only the first `need` set bits */             \
      if (lane == (G)) mykeep = kept;                                     \
      stop = 1;                                                           \
    } else {                                                              \
      nk += pc;                                                           \
      if (lane == (G)) mykeep = kept;                                     \
      unsigned long long keptv = kept >> psel;                            \
      REP32(UPDCUR)                                                       \
    }                                                                     \
  } while (0)

__global__ __attribute__((amdgpu_flat_work_group_size(64, 64),
                          amdgpu_waves_per_eu(1, 1))) void k_scan(
    const unsigned long long* __restrict__ mask,
    const float* __restrict__ sboxes,
    const float* __restrict__ sscores,
    float* __restrict__ rois,
    float* __restrict__ rsc) {
  const int b = blockIdx.x;
  const int lane = threadIdx.x;
  const int psel = lane >> 5;   // row parity this lane covers in pair loads
  const unsigned long long* M = mask + (size_t)b * MROWS * MW;

  REP32(DECLM)
  unsigned long long dA, dB;
  unsigned long long remv = 0ull;
  unsigned long long mykeep = 0ull;   // lane g (<32) holds group g's kept word
  int nk = 0, stop = 0;

  // prologue: group 0 into set A, diag(0)
  { const int gg = 0; REP32(MLA) }
  { int _row = lane; dA = (_row < PRE_K) ? M[(size_t)_row * MW + 0] : 0ull; }

  for (int g = 0; g < 32; g += 2) {
    GSTEP_CORE(g, MLB, UPDA, dA, dB);      // cur = A, prefetch into B
    if (stop) break;
    GSTEP_CORE(g + 1, MLA, UPDB, dB, dA);  // cur = B, prefetch into A
    if (stop) break;
  }

  // ---- write phase ----
  int pc = __popcll(mykeep);
  int pref = pc;
#pragma unroll
  for (int off = 1; off < 64; off <<= 1) {
    int v = __shfl_up(pref, off, 64);
    if (lane >= off) pref += v;
  }
  const int excl = pref - pc;
  const int Ktot = __shfl(pref, 63, 64);
  int rank = excl;
  unsigned long long ww = mykeep;
  while (ww) {
    int j = __builtin_ctzll(ww);
    ww &= ww - 1;
    int row = lane * 64 + j;
    ((float4*)rois)[(size_t)b * POST_K + rank] =
        ((const float4*)sboxes)[(size_t)b * PRE_K + row];
    rsc[(size_t)b * POST_K + rank] = sscores[(size_t)b * PRE_K + row];
    ++rank;
  }
  float4 pad = ((const float4*)sboxes)[(size_t)b * PRE_K + 0];
  for (int i = Ktot + lane; i < POST_K; i += 64) {
    ((float4*)rois)[(size_t)b * POST_K + i] = pad;
    rsc[(size_t)b * POST_K + i] = -1.0f;
  }
}

// ---------------- launch ----------------
extern "C" void kernel_launch(void* const* d_in, const int* in_sizes, int n_in,
                              void* d_out, int out_size, void* d_ws, size_t ws_size,
                              hipStream_t stream) {
  const float* feats    = (const float*)d_in[0];
  const float* img_info = (const float*)d_in[1];
  const float* w_cls    = (const float*)d_in[2];
  const float* b_cls    = (const float*)d_in[3];
  const float* w_reg    = (const float*)d_in[4];
  const float* b_reg    = (const float*)d_in[5];

  float* out = (float*)d_out;
  float* out_cls  = out;              // [2,208,336,3]  = 419328
  float* out_bbox = out + 419328;     // [2,208,336,12] = 1677312
  float* out_rois = out + 2096640;    // [2,1000,4]     = 8000
  float* out_rsc  = out + 2104640;    // [2,1000]       = 2000

  char* ws = (char*)d_ws;
  unsigned int* hist        = (unsigned int*)(ws + WS_HIST);
  unsigned int* hist2       = (unsigned int*)(ws + WS_HIST2);
  unsigned int* cand_count  = (unsigned int*)(ws + WS_CCNT);
  unsigned long long* cand  = (unsigned long long*)(ws + WS_CAND);
  float* sboxes             = (float*)(ws + WS_SBOX);
  float* sscores            = (float*)(ws + WS_SSC);
  unsigned long long* mask  = (unsigned long long*)(ws + WS_MASK);

  k_zero<<<(WS_ZERO_WORDS + 255) / 256, 256, 0, stream>>>((unsigned int*)ws, WS_ZERO_WORDS);
  k_head<<<dim3(512, NB), 256, 0, stream>>>(feats, w_cls, b_cls, w_reg, b_reg,
                                            out_cls, out_bbox, hist);
  k_hist2<<<dim3(128, NB), 256, 0, stream>>>(out_cls, hist, hist2);
  k_compact<<<dim3(128, NB), 256, 0, stream>>>(out_cls, hist, hist2,
                                               cand_count, cand);
  k_sort<<<NB, 1024, 0, stream>>>(cand, cand_count, out_bbox, img_info, sboxes, sscores);
  k_mask<<<dim3(528, 1, NB), 64, 0, stream>>>(sboxes, mask);
  k_scan<<<NB, 64, 0, stream>>>(mask, sboxes, sscores, out_rois, out_rsc);
}

// Round 12
// 391.543 us; speedup vs baseline: 1.0099x; 1.0099x over previous
//
#include <hip/hip_runtime.h>
#include <cstdint>
#include <cstddef>

// ---------------- problem constants ----------------
#define HH 208
#define WW 336
#define NA 3
#define NPER 209664      // H*W*A per image
#define NROWS 139776     // B*H*W
#define RPI 69888        // H*W rows per image
#define NB 2
#define PRE_K 2000
#define POST_K 1000
#define CAP 8192         // candidate capacity per image (power of 2 for bitonic)
#define MW 32            // 64-bit words per mask row (32*64 = 2048 >= 2000)
#define MROWS 2048
#define BBOX_CLIP_F 4.135166556742356f

// ---------------- ws layout (bytes) ----------------
#define WS_HIST   0
#define WS_HIST2  32768
#define WS_META   65536
#define WS_META24 65544
#define WS_CCNT   65552
#define WS_KEEPW  65568
#define WS_CAND   66080
#define WS_SBOX   197152
#define WS_SSC    261152
#define WS_MASK   277248
// zero [0, WS_KEEPW): hist, hist2, meta, counts. cand not zeroed
// (k_sort guards i<cc).
#define WS_ZERO_WORDS 16392

// ---------------- helpers ----------------
__device__ __forceinline__ float sigmoidf_ref(float x) {
  return __fdiv_rn(1.0f, __fadd_rn(1.0f, expf(-x)));
}
__device__ __forceinline__ unsigned int score_u(float logit) {
  float s = sigmoidf_ref(logit);            // s in (0,1), sign bit 0
  return __float_as_uint(s) | 0x80000000u;  // orderable
}

// broadcast 64-bit value from lane l (uniform l) via v_readlane — no LDS round trip
__device__ __forceinline__ unsigned long long bcast64(unsigned long long v, int l) {
  unsigned int lo = (unsigned int)__builtin_amdgcn_readlane((int)(unsigned int)v, l);
  unsigned int hi = (unsigned int)__builtin_amdgcn_readlane((int)(unsigned int)(v >> 32), l);
  return ((unsigned long long)hi << 32) | lo;
}

// descending suffix-select over a 4096-bin histogram, 256 threads.
__device__ __forceinline__ void suffix_select(const unsigned int* __restrict__ H,
                                              unsigned int C0in, unsigned int need,
                                              unsigned int base,
                                              unsigned int* __restrict__ csum,
                                              unsigned int* __restrict__ outBin,
                                              unsigned int* __restrict__ outC0) {
  const int t = threadIdx.x;
  unsigned int hb[16];
  unsigned int s = 0u;
#pragma unroll
  for (int q = 0; q < 16; ++q) {
    hb[q] = H[4095 - (t * 16 + q)];
    s += hb[q];
  }
  csum[t] = s;
  __syncthreads();
  for (int off = 1; off < 256; off <<= 1) {
    unsigned int v = (t >= off) ? csum[t - off] : 0u;
    __syncthreads();
    csum[t] += v;
    __syncthreads();
  }
  unsigned int excl = C0in + (csum[t] - s);
  if (excl < need && excl + s >= need) {
    unsigned int c = excl;
#pragma unroll
    for (int q = 0; q < 16; ++q) {
      c += hb[q];
      if (c >= need) {
        *outBin = base | (unsigned int)(4095 - (t * 16 + q));
        if (outC0) *outC0 = c - hb[q];
        break;
      }
    }
  }
}

// decode box for anchor n of image b; matches reference op-by-op (no FMA contraction)
__device__ __forceinline__ float4 decode_box(const float* __restrict__ bbox,
                                             int b, unsigned int n,
                                             float hmax, float wmax) {
  unsigned int a = n % 3u;
  unsigned int pix = n / 3u;
  unsigned int y = pix / (unsigned int)WW;
  unsigned int x = pix % (unsigned int)WW;
  float yc = ((float)y + 0.5f) * 4.0f;   // exact in f32
  float xc = ((float)x + 0.5f) * 4.0f;   // exact in f32
  float hx = (a == 0) ? 16.0f : ((a == 1) ? 22.4f : 11.2f);
  float hy = (a == 0) ? 16.0f : ((a == 1) ? 11.2f : 22.4f);
  float ay1 = __fsub_rn(yc, hy), ax1 = __fsub_rn(xc, hx);
  float ay2 = __fadd_rn(yc, hy), ax2 = __fadd_rn(xc, hx);
  float ah = __fsub_rn(ay2, ay1), aw = __fsub_rn(ax2, ax1);
  float acy = __fadd_rn(ay1, __fmul_rn(0.5f, ah));
  float acx = __fadd_rn(ax1, __fmul_rn(0.5f, aw));
  const float* d = bbox + ((size_t)b * NPER + n) * 4u;
  float dy = d[0], dx = d[1];
  float dh = fminf(fmaxf(d[2], -BBOX_CLIP_F), BBOX_CLIP_F);
  float dw = fminf(fmaxf(d[3], -BBOX_CLIP_F), BBOX_CLIP_F);
  float cy = __fadd_rn(__fmul_rn(dy, ah), acy);
  float cx = __fadd_rn(__fmul_rn(dx, aw), acx);
  float hh = __fmul_rn(expf(dh), ah);
  float wwv = __fmul_rn(expf(dw), aw);
  float y1 = __fsub_rn(cy, __fmul_rn(0.5f, hh));
  float x1 = __fsub_rn(cx, __fmul_rn(0.5f, wwv));
  float y2 = __fadd_rn(cy, __fmul_rn(0.5f, hh));
  float x2 = __fadd_rn(cx, __fmul_rn(0.5f, wwv));
  y1 = fminf(fmaxf(y1, 0.0f), hmax);
  x1 = fminf(fmaxf(x1, 0.0f), wmax);
  y2 = fminf(fmaxf(y2, 0.0f), hmax);
  x2 = fminf(fmaxf(x2, 0.0f), wmax);
  return make_float4(y1, x1, y2, x2);
}

// reference IoU, exact op order
__device__ __forceinline__ float iou_ref(float4 bi, float4 bj) {
  float yA = fmaxf(bi.x, bj.x);
  float xA = fmaxf(bi.y, bj.y);
  float yB = fminf(bi.z, bj.z);
  float xB = fminf(bi.w, bj.w);
  float inter = __fmul_rn(fmaxf(__fsub_rn(yB, yA), 0.0f),
                          fmaxf(__fsub_rn(xB, xA), 0.0f));
  float a1 = __fmul_rn(__fsub_rn(bi.z, bi.x), __fsub_rn(bi.w, bi.y));
  float a2 = __fmul_rn(__fsub_rn(bj.z, bj.x), __fsub_rn(bj.w, bj.y));
  float den = __fadd_rn(__fsub_rn(__fadd_rn(a1, a2), inter), 1e-8f);
  return __fdiv_rn(inter, den);
}

// ---------------- K0: zero ws prefix ----------------
__global__ void k_zero(unsigned int* __restrict__ p, int n) {
  int i = blockIdx.x * blockDim.x + threadIdx.x;
  if (i < n) p[i] = 0u;
}

// ---------------- K1: head GEMM + fused coarse histogram ----------------
// R7-best body (392.7us). Occupancy ledger (all measured): 3w+2row=392.7,
// 3w+1row=396.3 (R8), 4w+1row=402.3 (R9) — 2-row ILP at 3 waves/SIMD wins.
__global__ __launch_bounds__(256, 3) void k_head(
    const float* __restrict__ feats, const float* __restrict__ w_cls,
    const float* __restrict__ b_cls, const float* __restrict__ w_reg,
    const float* __restrict__ b_reg, float* __restrict__ out_cls,
    float* __restrict__ out_bbox, unsigned int* __restrict__ hist) {
  const int b = blockIdx.y;
  const int lane = threadIdx.x & 63;
  const int wid = blockIdx.x * (blockDim.x >> 6) + (threadIdx.x >> 6);
  const int nw = gridDim.x * (blockDim.x >> 6);
  const int k0 = lane << 2;
  const int l15 = lane & 15;
  const int ol = ((l15 & 1) << 3) | ((l15 & 2) << 1) | ((l15 & 4) >> 1) |
                 ((l15 & 8) >> 3);  // brev4 — this lane's final output

  __shared__ unsigned int h[4096];     // 16 KiB
  __shared__ float wt[16][256];        // 16 KiB, wt[o][c]
  for (int i = threadIdx.x; i < 4096; i += blockDim.x) {
    h[i] = 0u;
    const int o = i >> 8, c = i & 255;
    wt[o][c] = (o < 3) ? w_cls[c * 3 + o]
                       : (o < 15 ? w_reg[c * 12 + (o - 3)] : 0.0f);
  }
  __syncthreads();

  // one-time weight fetch into named registers: wj = wt[ol^j][k0..k0+3]
  float4 w0  = *(const float4*)&wt[ol ^ 0][k0];
  float4 w1  = *(const float4*)&wt[ol ^ 1][k0];
  float4 w2  = *(const float4*)&wt[ol ^ 2][k0];
  float4 w3  = *(const float4*)&wt[ol ^ 3][k0];
  float4 w4  = *(const float4*)&wt[ol ^ 4][k0];
  float4 w5  = *(const float4*)&wt[ol ^ 5][k0];
  float4 w6  = *(const float4*)&wt[ol ^ 6][k0];
  float4 w7  = *(const float4*)&wt[ol ^ 7][k0];
  float4 w8  = *(const float4*)&wt[ol ^ 8][k0];
  float4 w9  = *(const float4*)&wt[ol ^ 9][k0];
  float4 w10 = *(const float4*)&wt[ol ^ 10][k0];
  float4 w11 = *(const float4*)&wt[ol ^ 11][k0];
  float4 w12 = *(const float4*)&wt[ol ^ 12][k0];
  float4 w13 = *(const float4*)&wt[ol ^ 13][k0];
  float4 w14 = *(const float4*)&wt[ol ^ 14][k0];
  float4 w15 = *(const float4*)&wt[ol ^ 15][k0];
  float bias = (ol < 3) ? b_cls[ol] : (ol < 15 ? b_reg[ol - 3] : 0.0f);

  // pin: values become opaque -> compiler must keep them register-resident.
#define PIN4(W) asm volatile("" : "+v"(W.x), "+v"(W.y), "+v"(W.z), "+v"(W.w))
  PIN4(w0);  PIN4(w1);  PIN4(w2);  PIN4(w3);
  PIN4(w4);  PIN4(w5);  PIN4(w6);  PIN4(w7);
  PIN4(w8);  PIN4(w9);  PIN4(w10); PIN4(w11);
  PIN4(w12); PIN4(w13); PIN4(w14); PIN4(w15);
#undef PIN4
  asm volatile("" : "+v"(bias));

  for (int rr = wid; rr < RPI; rr += 2 * nw) {
    const int rr1 = rr + nw;
    const int has1 = (rr1 < RPI);
    const int r0 = b * RPI + rr;
    const int r1 = b * RPI + (has1 ? rr1 : rr);
    const float4 f0 = *(const float4*)(feats + (size_t)r0 * 256 + k0);
    const float4 f1 = *(const float4*)(feats + (size_t)r1 * 256 + k0);
    float a0[16], a1[16];
#define STEPJ(J, W)                                                        \
    {                                                                      \
      a0[J] = f0.x * W.x; a0[J] += f0.y * W.y;                             \
      a0[J] += f0.z * W.z; a0[J] += f0.w * W.w;                            \
      a1[J] = f1.x * W.x; a1[J] += f1.y * W.y;                             \
      a1[J] += f1.z * W.z; a1[J] += f1.w * W.w;                            \
    }
    STEPJ(0, w0)   STEPJ(1, w1)   STEPJ(2, w2)   STEPJ(3, w3)
    STEPJ(4, w4)   STEPJ(5, w5)   STEPJ(6, w6)   STEPJ(7, w7)
    STEPJ(8, w8)   STEPJ(9, w9)   STEPJ(10, w10) STEPJ(11, w11)
    STEPJ(12, w12) STEPJ(13, w13) STEPJ(14, w14) STEPJ(15, w15)
#undef STEPJ
#pragma unroll
    for (int s = 0; s < 8; ++s) {
      a0[s] += __shfl_xor(a0[8 + s], 1, 64);
      a1[s] += __shfl_xor(a1[8 + s], 1, 64);
    }
#pragma unroll
    for (int s = 0; s < 4; ++s) {
      a0[s] += __shfl_xor(a0[4 + s], 2, 64);
      a1[s] += __shfl_xor(a1[4 + s], 2, 64);
    }
#pragma unroll
    for (int s = 0; s < 2; ++s) {
      a0[s] += __shfl_xor(a0[2 + s], 4, 64);
      a1[s] += __shfl_xor(a1[2 + s], 4, 64);
    }
    a0[0] += __shfl_xor(a0[1], 8, 64);
    a1[0] += __shfl_xor(a1[1], 8, 64);
    a0[0] += __shfl_xor(a0[0], 16, 64);
    a1[0] += __shfl_xor(a1[0], 16, 64);
    a0[0] += __shfl_xor(a0[0], 32, 64);
    a1[0] += __shfl_xor(a1[0], 32, 64);
    if (lane < 16 && ol < 15) {
      float v0 = a0[0] + bias;
      if (ol < 3) {
        out_cls[(size_t)r0 * 3 + ol] = v0;
        atomicAdd(&h[score_u(v0) >> 20], 1u);
      } else {
        out_bbox[(size_t)r0 * 12 + (ol - 3)] = v0;
      }
      if (has1) {
        float v1 = a1[0] + bias;
        if (ol < 3) {
          out_cls[(size_t)r1 * 3 + ol] = v1;
          atomicAdd(&h[score_u(v1) >> 20], 1u);
        } else {
          out_bbox[(size_t)r1 * 12 + (ol - 3)] = v1;
        }
      }
    }
  }
  __syncthreads();
  // scores cluster near 0.5 → only a handful of nonzero bins per block
  for (int i = threadIdx.x; i < 4096; i += blockDim.x)
    if (h[i]) atomicAdd(&hist[b * 4096 + i], h[i]);
}

// ---------------- K2: refine histogram (T computed redundantly per block) --
__global__ __launch_bounds__(256) void k_hist2(const float* __restrict__ out_cls,
                                               const unsigned int* __restrict__ hist,
                                               unsigned int* __restrict__ hist2) {
  const int b = blockIdx.y;
  __shared__ unsigned int h[4096];
  __shared__ unsigned int csum[256];
  __shared__ unsigned int Tsh;
  for (int i = threadIdx.x; i < 4096; i += blockDim.x) h[i] = 0u;
  suffix_select(hist + b * 4096, 0u, PRE_K, 0u, csum, &Tsh, nullptr);
  __syncthreads();
  const unsigned int T = Tsh;
  for (int i = blockIdx.x * blockDim.x + threadIdx.x; i < NPER;
       i += gridDim.x * blockDim.x) {
    unsigned int u = score_u(out_cls[(size_t)b * NPER + i]);
    if ((u >> 20) == T) atomicAdd(&h[(u >> 8) & 0xFFFu], 1u);
  }
  __syncthreads();
  for (int i = threadIdx.x; i < 4096; i += blockDim.x)
    if (h[i]) atomicAdd(&hist2[b * 4096 + i], h[i]);
}

// ---------------- K3: compact (T24 computed redundantly per block) ---------
__global__ __launch_bounds__(256) void k_compact(const float* __restrict__ out_cls,
                                                 const unsigned int* __restrict__ hist,
                                                 const unsigned int* __restrict__ hist2,
                                                 unsigned int* __restrict__ cand_count,
                                                 unsigned long long* __restrict__ cand) {
  const int b = blockIdx.y;
  __shared__ unsigned int csum[256];
  __shared__ unsigned int Tsh, C0sh, T24sh;
  suffix_select(hist + b * 4096, 0u, PRE_K, 0u, csum, &Tsh, &C0sh);
  __syncthreads();
  const unsigned int T = Tsh, C0 = C0sh;
  suffix_select(hist2 + b * 4096, C0, PRE_K, T << 12, csum, &T24sh, nullptr);
  __syncthreads();
  const unsigned int T24 = T24sh;
  for (int i = blockIdx.x * blockDim.x + threadIdx.x; i < NPER;
       i += gridDim.x * blockDim.x) {
    unsigned int u = score_u(out_cls[(size_t)b * NPER + i]);
    if ((u >> 8) >= T24) {
      unsigned int pos = atomicAdd(&cand_count[b], 1u);
      if (pos < CAP)
        cand[(size_t)b * CAP + pos] =
            ((unsigned long long)u << 32) | (unsigned int)(~(unsigned int)i);
    }
  }
}

// ---------------- K4: adaptive bitonic sort (desc) + gather/decode top-2000 -
__global__ __launch_bounds__(1024) void k_sort(const unsigned long long* __restrict__ cand,
                                               const unsigned int* __restrict__ cand_count,
                                               const float* __restrict__ out_bbox,
                                               const float* __restrict__ img_info,
                                               float* __restrict__ sboxes,
                                               float* __restrict__ sscores) {
  const int b = blockIdx.x;
  const int t = threadIdx.x;
  __shared__ unsigned long long keys[CAP];   // 64 KiB
  unsigned int cc = cand_count[b];
  if (cc > CAP) cc = CAP;
  int n = 2048;
  while ((unsigned int)n < cc) n <<= 1;
  for (int i = t; i < n; i += 1024)
    keys[i] = (i < (int)cc) ? cand[(size_t)b * CAP + i] : 0ull;
  __syncthreads();
  for (int k = 2; k <= n; k <<= 1) {
    for (int j = k >> 1; j > 0; j >>= 1) {
      for (int i = t; i < n; i += 1024) {
        int ixj = i ^ j;
        if (ixj > i) {
          unsigned long long a = keys[i], c = keys[ixj];
          bool up = ((i & k) == 0);
          bool sw = up ? (a < c) : (a > c);   // descending overall
          if (sw) { keys[i] = c; keys[ixj] = a; }
        }
      }
      __syncthreads();
    }
  }
  const float hmax = img_info[b * 2 + 0];
  const float wmax = img_info[b * 2 + 1];
  for (int i = t; i < PRE_K; i += 1024) {
    unsigned long long key = keys[i];
    unsigned int u = (unsigned int)(key >> 32);
    unsigned int idx = ~(unsigned int)(key & 0xFFFFFFFFull);
    float sc = __uint_as_float(u & 0x7FFFFFFFu);
    float4 bx = decode_box(out_bbox, b, idx, hmax, wmax);
    ((float4*)sboxes)[(size_t)b * PRE_K + i] = bx;
    sscores[(size_t)b * PRE_K + i] = sc;
  }
}

// ---------------- K5: pairwise suppression mask (upper-triangle grid) ------
__global__ __launch_bounds__(64) void k_mask(const float* __restrict__ sboxes,
                                             unsigned long long* __restrict__ mask) {
  const int b = blockIdx.z;
  const int p = blockIdx.x;
  const int q = 527 - p;
  const int kk = (int)((sqrtf((float)(8 * q + 1)) - 1.0f) * 0.5f);
  const int rb = 31 - kk;
  const int cb = 31 - (q - kk * (kk + 1) / 2);
  const int t = threadIdx.x;
  __shared__ float4 cbox[64];
  const int col0 = cb * 64;
  {
    int c = col0 + t;
    cbox[t] = (c < PRE_K) ? ((const float4*)sboxes)[(size_t)b * PRE_K + c]
                          : make_float4(0.f, 0.f, 0.f, 0.f);
  }
  __syncthreads();
  const int i = rb * 64 + t;
  if (i >= PRE_K) return;
  float4 bi = ((const float4*)sboxes)[(size_t)b * PRE_K + i];
  unsigned long long bits = 0ull;
#pragma unroll 8
  for (int j = 0; j < 64; ++j) {
    int c = col0 + j;
    if (c > i && c < PRE_K) {
      if (iou_ref(bi, cbox[j]) > 0.7f) bits |= (1ull << j);
    }
  }
  mask[((size_t)b * MROWS + i) * MW + cb] = bits;
}

// ---------------- K6: keep scan + rank write (merged) ----------------
// v3: SINGLE-buffered named-scalar prefetch. R11 showed the double-buffer
// design cannot fit (needs ~145 VGPR, allocator gave 132 -> still spilled;
// k_scan stayed ~84us at ~96% stall on the active CU). The only true serial
// dependency is diag(g) (needed by walk g, prefetched at step g-1) and remv.
// Group g's 32 UPD words are consumed AFTER the walk, so issuing them at the
// top of step g hides their latency under the walk. Demand: 32 u64 buffer
// (64 VGPR) + d/dnext + state ~= 95 VGPR — fits with no spill.
// Load indices/guards/walk/trim identical -> bit-identical keep set.
#define REP32(F)                                                          \
  F(0) F(1) F(2) F(3) F(4) F(5) F(6) F(7)                                 \
  F(8) F(9) F(10) F(11) F(12) F(13) F(14) F(15)                           \
  F(16) F(17) F(18) F(19) F(20) F(21) F(22) F(23)                         \
  F(24) F(25) F(26) F(27) F(28) F(29) F(30) F(31)

#define DECLS(K) unsigned long long mS##K;
// load group g's word for rows 2K+psel, column lane&31 (upper-triangle only)
#define MLS(K) mS##K = ((g * 64 + 2 * K + psel) < PRE_K && (lane & 31) >= g) \
                           ? M[(size_t)g * 2048 + 64 * K + lane] : 0ull;
#define UPDS(K) { unsigned long long sel_ = 0ull - ((keptv >> (2 * K)) & 1ull); \
                  remv |= mS##K & sel_; }

__global__ __attribute__((amdgpu_flat_work_group_size(64, 64),
                          amdgpu_waves_per_eu(1, 1))) void k_scan(
    const unsigned long long* __restrict__ mask,
    const float* __restrict__ sboxes,
    const float* __restrict__ sscores,
    float* __restrict__ rois,
    float* __restrict__ rsc) {
  const int b = blockIdx.x;
  const int lane = threadIdx.x;
  const int psel = lane >> 5;   // row parity this lane covers in pair loads
  const unsigned long long* M = mask + (size_t)b * MROWS * MW;

  REP32(DECLS)
  unsigned long long d, dnext;
  unsigned long long remv = 0ull;
  unsigned long long mykeep = 0ull;   // lane g (<32) holds group g's kept word
  int nk = 0, stop = 0;

  // prologue: diag(0)
  d = (lane < PRE_K) ? M[(size_t)lane * MW + 0] : 0ull;

  for (int g = 0; g < 32; ++g) {
    // issue group g's UPD words (consumed after the walk — latency hidden)
    REP32(MLS)
    // issue next diag (the true serial prefetch)
    {
      int _row = (g + 1) * 64 + lane;
      dnext = ((g + 1) < 32 && _row < PRE_K)
                  ? M[(size_t)_row * MW + (g + 1)] : 0ull;
    }
    // ---- walk group g using diag d (loaded one step ahead) ----
    unsigned long long w = bcast64(remv, g) | bcast64(remv, g + 32);
    unsigned long long alive = ~w;
    if (g == 31) alive &= (1ull << (PRE_K - 31 * 64)) - 1ull;
    unsigned long long kept = 0ull;
    while (alive) {
      int j = __builtin_ctzll(alive);
      unsigned long long bit = 1ull << j;
      kept |= bit;
      unsigned long long dj = bcast64(d, j);
      alive &= ~(dj | bit);
    }
    int pc = __popcll(kept);
    if (nk + pc >= POST_K) {
      int need = POST_K - nk;
      unsigned long long k2 = kept;
      for (int _t = 0; _t < need; ++_t) k2 &= k2 - 1;
      kept ^= k2;   // keep only the first `need` set bits
      if (lane == g) mykeep = kept;
      stop = 1;
    } else {
      nk += pc;
      if (lane == g) mykeep = kept;
      unsigned long long keptv = kept >> psel;
      REP32(UPDS)
    }
    if (stop) break;
    d = dnext;
  }

  // ---- write phase ----
  int pc = __popcll(mykeep);
  int pref = pc;
#pragma unroll
  for (int off = 1; off < 64; off <<= 1) {
    int v = __shfl_up(pref, off, 64);
    if (lane >= off) pref += v;
  }
  const int excl = pref - pc;
  const int Ktot = __shfl(pref, 63, 64);
  int rank = excl;
  unsigned long long ww = mykeep;
  while (ww) {
    int j = __builtin_ctzll(ww);
    ww &= ww - 1;
    int row = lane * 64 + j;
    ((float4*)rois)[(size_t)b * POST_K + rank] =
        ((const float4*)sboxes)[(size_t)b * PRE_K + row];
    rsc[(size_t)b * POST_K + rank] = sscores[(size_t)b * PRE_K + row];
    ++rank;
  }
  float4 pad = ((const float4*)sboxes)[(size_t)b * PRE_K + 0];
  for (int i = Ktot + lane; i < POST_K; i += 64) {
    ((float4*)rois)[(size_t)b * POST_K + i] = pad;
    rsc[(size_t)b * POST_K + i] = -1.0f;
  }
}

// ---------------- launch ----------------
extern "C" void kernel_launch(void* const* d_in, const int* in_sizes, int n_in,
                              void* d_out, int out_size, void* d_ws, size_t ws_size,
                              hipStream_t stream) {
  const float* feats    = (const float*)d_in[0];
  const float* img_info = (const float*)d_in[1];
  const float* w_cls    = (const float*)d_in[2];
  const float* b_cls    = (const float*)d_in[3];
  const float* w_reg    = (const float*)d_in[4];
  const float* b_reg    = (const float*)d_in[5];

  float* out = (float*)d_out;
  float* out_cls  = out;              // [2,208,336,3]  = 419328
  float* out_bbox = out + 419328;     // [2,208,336,12] = 1677312
  float* out_rois = out + 2096640;    // [2,1000,4]     = 8000
  float* out_rsc  = out + 2104640;    // [2,1000]       = 2000

  char* ws = (char*)d_ws;
  unsigned int* hist        = (unsigned int*)(ws + WS_HIST);
  unsigned int* hist2       = (unsigned int*)(ws + WS_HIST2);
  unsigned int* cand_count  = (unsigned int*)(ws + WS_CCNT);
  unsigned long long* cand  = (unsigned long long*)(ws + WS_CAND);
  float* sboxes             = (float*)(ws + WS_SBOX);
  float* sscores            = (float*)(ws + WS_SSC);
  unsigned long long* mask  = (unsigned long long*)(ws + WS_MASK);

  k_zero<<<(WS_ZERO_WORDS + 255) / 256, 256, 0, stream>>>((unsigned int*)ws, WS_ZERO_WORDS);
  k_head<<<dim3(512, NB), 256, 0, stream>>>(feats, w_cls, b_cls, w_reg, b_reg,
                                            out_cls, out_bbox, hist);
  k_hist2<<<dim3(128, NB), 256, 0, stream>>>(out_cls, hist, hist2);
  k_compact<<<dim3(128, NB), 256, 0, stream>>>(out_cls, hist, hist2,
                                               cand_count, cand);
  k_sort<<<NB, 1024, 0, stream>>>(cand, cand_count, out_bbox, img_info, sboxes, sscores);
  k_mask<<<dim3(528, 1, NB), 64, 0, stream>>>(sboxes, mask);
  k_scan<<<NB, 64, 0, stream>>>(mask, sboxes, sscores, out_rois, out_rsc);
}